// Round 14
// baseline (260.651 us; speedup 1.0000x reference)
//
#include <hip/hip_runtime.h>
#include <math.h>

#define N_ 16
#define C_ 4
#define F_ 257
#define T_ 1000
#define B_ 8
#define K_ 80
#define BK_ 640
#define TT_ 16
#define NT_ 63            // ceil(1000/16)
#define NBLK (N_ * NT_)   // 1008
#define MSTR 264          // magS row stride (f32 words); rows 16B-aligned

typedef _Float16 half4 __attribute__((ext_vector_type(4)));
typedef _Float16 half8 __attribute__((ext_vector_type(8)));
typedef float f32x4 __attribute__((ext_vector_type(4)));

#define WSCALE   256.0f          // dodge f16 subnormals in w0
#define WUNSCALE 0.00390625f     // 2^-8

// d_ws byte offsets
#define WP0_OFF   0               // 80 frags * 64 lanes * 4 halves = 40960 B
#define WP1_OFF   (64 * 1024)
#define WP2_OFF   (128 * 1024)
#define WTAIL_OFF (192 * 1024)    // 80 f32
#define PART_OFF  (256 * 1024)    // NBLK*16 doubles
#define SS_OFF    (PART_OFF + NBLK * 16 * 8)

// ---- pack w_proj into 16x16x16 B-fragment layout, 3-term f16 split --------
// frag blk = ch*10 + kt*2 + ksub. lane L, elem j:
//   B[f = ch*32 + ksub*16 + 4*(L/16) + j][k = kt*16 + L%16], scaled by 256.
__global__ __launch_bounds__(80) void k_wt(const float* __restrict__ wp,
                                           _Float16* __restrict__ wp0,
                                           _Float16* __restrict__ wp1,
                                           _Float16* __restrict__ wp2,
                                           float* __restrict__ wtail) {
    int blk = blockIdx.x;
    int tid = threadIdx.x;
    if (blk < 80) {
        if (tid < 64) {
            int ch = blk / 10, r = blk % 10, kt = r >> 1, ksub = r & 1;
            int k = kt * 16 + (tid & 15);
            int fb = ch * 32 + ksub * 16 + 4 * (tid >> 4);
#pragma unroll
            for (int j = 0; j < 4; ++j) {
                float w = wp[k * F_ + fb + j] * WSCALE;
                _Float16 w0 = (_Float16)w;
                float r1 = (w - (float)w0) * 2048.0f;
                _Float16 w1 = (_Float16)r1;
                float r2 = (r1 - (float)w1) * 2048.0f;
                _Float16 w2 = (_Float16)r2;
                size_t o = ((size_t)blk * 64 + tid) * 4 + j;
                wp0[o] = w0; wp1[o] = w1; wp2[o] = w2;
            }
        }
    } else {
        wtail[tid] = wp[tid * F_ + 256];   // f = 256 column, f32 (no scaling)
    }
}

// Fused beamform(f32,LDS) + 3-term-split f16 MFMA GEMM + relu+log + BN sums.
// 512 threads = 8 waves; wave = beam b. Block = (n, 16-t tile).
__global__ __launch_bounds__(512, 4) void k_fused(
    const float* __restrict__ xr, const float* __restrict__ xi,
    const float* __restrict__ wr, const float* __restrict__ wi,
    const _Float16* __restrict__ wp0, const _Float16* __restrict__ wp1,
    const _Float16* __restrict__ wp2, const float* __restrict__ wtail,
    float* __restrict__ out, double* __restrict__ partials) {

    const int tid = threadIdx.x;
    const int bid = blockIdx.x;
    const int tt = bid % NT_;
    const int n  = bid / NT_;
    const int t0 = tt * TT_;

    __shared__ __attribute__((aligned(16))) float magS[2][TT_][MSTR];  // 33.8 KB
    __shared__ __attribute__((aligned(16))) _Float16 wfS[2][3][2560];  // 30 KB
    __shared__ float wtS[80];
    __shared__ float magT[TT_][B_];

    const int lane = tid & 63;
    const int wv   = tid >> 6;                // wave id == beam b

    const int sfr = tid >> 4;                 // staging f-row 0..31
    const int t_s = tid & 15;                 // staging t 0..15
    const int tg  = t0 + t_s;
    const bool tld = (tg < T_);

    f32x4 accM[5], acc1[5], acc2[5];
#pragma unroll
    for (int kt = 0; kt < 5; ++kt) {
        accM[kt] = (f32x4)0.0f;
        acc1[kt] = (f32x4)0.0f;
        acc2[kt] = (f32x4)0.0f;
    }

    const float* xrn = xr + (size_t)n * C_ * F_ * T_;
    const float* xin = xi + (size_t)n * C_ * F_ * T_;

    if (tid < 80) wtS[tid] = wtail[tid];

    // -------- prefetch x for chunk 0 (f = sfr) --------
    float pxr[C_], pxi[C_];
    if (tld) {
#pragma unroll
        for (int c = 0; c < C_; ++c) {
            pxr[c] = xrn[((size_t)c * F_ + sfr) * T_ + tg];
            pxi[c] = xin[((size_t)c * F_ + sfr) * T_ + tg];
        }
    }

    for (int ch = 0; ch < 8; ++ch) {
        const int f0 = ch * 32;
        const int f  = f0 + sfr;
        const int pb = ch & 1;

        // ---- stage w fragments: 3 terms x 2560 halves = 960 x 16B ----
#pragma unroll
        for (int r = 0; r < 2; ++r) {
            int idx = tid + r * 512;
            if (idx < 960) {
                int term = idx / 320;
                int u = idx - term * 320;
                const _Float16* src =
                    (term == 0 ? wp0 : (term == 1 ? wp1 : wp2)) + ch * 2560 + u * 8;
                *(half8*)&wfS[pb][term][u * 8] = *(const half8*)src;
            }
        }

        // ---- beamform mag (f32) into magS[pb]: 8 b at (f, tg) ----
        {
            float m[B_];
            if (tld) {
                const float* wrp = wr + (size_t)f * B_ * C_;
                const float* wip = wi + (size_t)f * B_ * C_;
#pragma unroll
                for (int b = 0; b < B_; ++b) {
                    float4 wrv = *(const float4*)(wrp + b * C_);
                    float4 wiv = *(const float4*)(wip + b * C_);
                    float br  = pxr[0] * wrv.x + pxr[1] * wrv.y + pxr[2] * wrv.z + pxr[3] * wrv.w
                              - pxi[0] * wiv.x - pxi[1] * wiv.y - pxi[2] * wiv.z - pxi[3] * wiv.w;
                    float bi2 = pxi[0] * wrv.x + pxi[1] * wrv.y + pxi[2] * wrv.z + pxi[3] * wrv.w
                              + pxr[0] * wiv.x + pxr[1] * wiv.y + pxr[2] * wiv.z + pxr[3] * wiv.w;
                    m[b] = sqrtf(br * br + bi2 * bi2 + 1e-5f);
                }
            } else {
#pragma unroll
                for (int b = 0; b < B_; ++b) m[b] = 0.f;
            }
            *(float4*)&magS[pb][t_s][sfr * 8] = make_float4(m[0], m[1], m[2], m[3]);
            *(float4*)&magS[pb][t_s][sfr * 8 + 4] = make_float4(m[4], m[5], m[6], m[7]);
        }

        // ---- prefetch x for ch+1 ----
        if (ch < 7 && tld) {
            const int f2 = f0 + 32 + sfr;
#pragma unroll
            for (int c = 0; c < C_; ++c) {
                pxr[c] = xrn[((size_t)c * F_ + f2) * T_ + tg];
                pxi[c] = xin[((size_t)c * F_ + f2) * T_ + tg];
            }
        }

        __syncthreads();

        // ---- MFMA GEMM (16x16x16f16, documented layout): 2 k-subtiles ----
        {
            const int tA = lane & 15;
            const int g  = lane >> 4;
#pragma unroll
            for (int ks = 0; ks < 2; ++ks) {
                half4 a0, a1, a2;
#pragma unroll
                for (int j = 0; j < 4; ++j) {
                    float v = magS[pb][tA][(ks * 16 + 4 * g + j) * 8 + wv];
                    _Float16 h0 = (_Float16)v;
                    float r1 = (v - (float)h0) * 2048.0f;
                    _Float16 h1 = (_Float16)r1;
                    float r2 = (r1 - (float)h1) * 2048.0f;
                    a0[j] = h0; a1[j] = h1; a2[j] = (_Float16)r2;
                }
#pragma unroll
                for (int kt = 0; kt < 5; ++kt) {
                    int fi = ((kt * 2 + ks) * 64 + lane) * 4;
                    half4 b0 = *(const half4*)&wfS[pb][0][fi];
                    half4 b1 = *(const half4*)&wfS[pb][1][fi];
                    half4 b2 = *(const half4*)&wfS[pb][2][fi];
                    accM[kt] = __builtin_amdgcn_mfma_f32_16x16x16f16(a0, b0, accM[kt], 0, 0, 0);
                    acc1[kt] = __builtin_amdgcn_mfma_f32_16x16x16f16(a0, b1, acc1[kt], 0, 0, 0);
                    acc1[kt] = __builtin_amdgcn_mfma_f32_16x16x16f16(a1, b0, acc1[kt], 0, 0, 0);
                    acc2[kt] = __builtin_amdgcn_mfma_f32_16x16x16f16(a0, b2, acc2[kt], 0, 0, 0);
                    acc2[kt] = __builtin_amdgcn_mfma_f32_16x16x16f16(a1, b1, acc2[kt], 0, 0, 0);
                    acc2[kt] = __builtin_amdgcn_mfma_f32_16x16x16f16(a2, b0, acc2[kt], 0, 0, 0);
                }
            }
        }
    }

    // ---- tail f = 256: f32 mag into magT ----
    if (tid < 128) {
        int trow = tid >> 3;
        int b = tid & 7;
        int t = t0 + trow;
        float v = 0.f;
        if (t < T_) {
            const float* wrp = wr + (size_t)(256 * B_ + b) * C_;
            const float* wip = wi + (size_t)(256 * B_ + b) * C_;
            float br = 0.f, bi2 = 0.f;
#pragma unroll
            for (int c = 0; c < C_; ++c) {
                float xrv = xrn[((size_t)c * F_ + 256) * T_ + t];
                float xiv = xin[((size_t)c * F_ + 256) * T_ + t];
                br  += xrv * wrp[c] - xiv * wip[c];
                bi2 += xiv * wrp[c] + xrv * wip[c];
            }
            v = sqrtf(br * br + bi2 * bi2 + 1e-5f);
        }
        magT[trow][b] = v;
    }
    __syncthreads();

    // ---- epilogue: combine 3-term accs (unscale) + tail, relu+log, BN ----
    const int col = lane & 15;
    const int g   = lane >> 4;
    float s1 = 0.f, s2 = 0.f;
#pragma unroll
    for (int kt = 0; kt < 5; ++kt) {
        f32x4 r = (accM[kt] + 4.8828125e-4f * acc1[kt]
                   + 2.384185791015625e-7f * acc2[kt]) * WUNSCALE;
#pragma unroll
        for (int reg = 0; reg < 4; ++reg) {
            int trow = 4 * g + reg;
            int t = t0 + trow;
            float sum = r[reg] + magT[trow][wv] * wtS[kt * 16 + col];
            if (t < T_) {
                float v = fmaxf(sum, 0.0f);
                v = __logf(v + 1e-5f);
                out[((size_t)n * T_ + t) * BK_ + wv * K_ + kt * 16 + col] = v;
                s1 += v;
                s2 += v * v;
            }
        }
    }
    double d1 = (double)s1, d2 = (double)s2;
#pragma unroll
    for (int off = 32; off; off >>= 1) {
        d1 += __shfl_xor(d1, off);
        d2 += __shfl_xor(d2, off);
    }
    if (lane == 0) {
        partials[(size_t)bid * 16 + wv] = d1;
        partials[(size_t)bid * 16 + 8 + wv] = d2;
    }
}

// ---------------- reduce partials -> per-channel scale/shift ----------------
__global__ __launch_bounds__(256) void k_bnstats(
    const double* __restrict__ partials,
    const float* __restrict__ gamma, const float* __restrict__ beta,
    float* __restrict__ ss) {
    const int b = threadIdx.x >> 5;
    const int i = threadIdx.x & 31;
    double s1 = 0.0, s2 = 0.0;
    for (int j = i; j < NBLK; j += 32) {
        s1 += partials[(size_t)j * 16 + b];
        s2 += partials[(size_t)j * 16 + 8 + b];
    }
#pragma unroll
    for (int off = 16; off; off >>= 1) {
        s1 += __shfl_down(s1, off);
        s2 += __shfl_down(s2, off);
    }
    if (i == 0) {
        const double cnt = (double)N_ * T_ * K_;
        double mean = s1 / cnt;
        double var = s2 / cnt - mean * mean;
        float scale = gamma[b] * (float)(1.0 / sqrt(var + 1e-5));
        float shift = beta[b] - (float)mean * scale;
        ss[b] = scale;
        ss[B_ + b] = shift;
    }
}

// ---------------- apply BN in place over d_out ----------------
__global__ __launch_bounds__(256) void k_bnapply(float* __restrict__ out,
                                                 const float* __restrict__ ss) {
    size_t i4 = (size_t)blockIdx.x * 256 + threadIdx.x;
    int k4 = (int)(i4 % (BK_ / 4));
    int b = k4 / (K_ / 4);
    float scale = ss[b], shift = ss[B_ + b];
    float4* p = (float4*)out + i4;
    float4 v = *p;
    v.x = v.x * scale + shift;
    v.y = v.y * scale + shift;
    v.z = v.z * scale + shift;
    v.w = v.w * scale + shift;
    *p = v;
}

extern "C" void kernel_launch(void* const* d_in, const int* in_sizes, int n_in,
                              void* d_out, int out_size, void* d_ws, size_t ws_size,
                              hipStream_t stream) {
    const float* xr = (const float*)d_in[0];
    const float* xi = (const float*)d_in[1];
    const float* wr = (const float*)d_in[2];
    const float* wi = (const float*)d_in[3];
    const float* w_proj = (const float*)d_in[4];
    const float* gamma = (const float*)d_in[5];
    const float* beta = (const float*)d_in[6];
    float* out = (float*)d_out;

    _Float16* wp0 = (_Float16*)((char*)d_ws + WP0_OFF);
    _Float16* wp1 = (_Float16*)((char*)d_ws + WP1_OFF);
    _Float16* wp2 = (_Float16*)((char*)d_ws + WP2_OFF);
    float* wtail = (float*)((char*)d_ws + WTAIL_OFF);
    double* partials = (double*)((char*)d_ws + PART_OFF);
    float* ss = (float*)((char*)d_ws + SS_OFF);

    k_wt<<<81, 80, 0, stream>>>(w_proj, wp0, wp1, wp2, wtail);
    k_fused<<<NBLK, 512, 0, stream>>>(xr, xi, wr, wi, wp0, wp1, wp2, wtail, out, partials);
    k_bnstats<<<1, 256, 0, stream>>>(partials, gamma, beta, ss);
    k_bnapply<<<10000, 256, 0, stream>>>(out, ss);
}

// Round 15
// 171.826 us; speedup vs baseline: 1.5170x; 1.5170x over previous
//
#include <hip/hip_runtime.h>
#include <math.h>

#define N_ 16
#define C_ 4
#define F_ 257
#define T_ 1000
#define B_ 8
#define K_ 80
#define BK_ 640
#define TT_ 16
#define NT_ 63            // ceil(1000/16)
#define NBLK (N_ * NT_)   // 1008
#define MSTR 264          // magS row stride (f32 words); rows 16B-aligned

typedef _Float16 half4 __attribute__((ext_vector_type(4)));
typedef _Float16 half8 __attribute__((ext_vector_type(8)));
typedef float f32x4 __attribute__((ext_vector_type(4)));

#define WSCALE   256.0f          // dodge f16 subnormals in w0
#define WUNSCALE 0.00390625f     // 2^-8

// d_ws byte offsets
#define WP0_OFF   0               // 80 frags * 64 lanes * 4 halves = 40960 B
#define WP1_OFF   (64 * 1024)
#define WP2_OFF   (128 * 1024)
#define WTAIL_OFF (192 * 1024)    // 80 f32
#define PART_OFF  (256 * 1024)    // NBLK*16 doubles
#define SS_OFF    (PART_OFF + NBLK * 16 * 8)

// ---- pack w_proj into 16x16x16 B-fragment layout, 3-term f16 split --------
// frag blk = ch*10 + kt*2 + ksub. lane L, elem j:
//   B[f = ch*32 + ksub*16 + 4*(L/16) + j][k = kt*16 + L%16], scaled by 256.
__global__ __launch_bounds__(80) void k_wt(const float* __restrict__ wp,
                                           _Float16* __restrict__ wp0,
                                           _Float16* __restrict__ wp1,
                                           _Float16* __restrict__ wp2,
                                           float* __restrict__ wtail) {
    int blk = blockIdx.x;
    int tid = threadIdx.x;
    if (blk < 80) {
        if (tid < 64) {
            int ch = blk / 10, r = blk % 10, kt = r >> 1, ksub = r & 1;
            int k = kt * 16 + (tid & 15);
            int fb = ch * 32 + ksub * 16 + 4 * (tid >> 4);
#pragma unroll
            for (int j = 0; j < 4; ++j) {
                float w = wp[k * F_ + fb + j] * WSCALE;
                _Float16 w0 = (_Float16)w;
                float r1 = (w - (float)w0) * 2048.0f;
                _Float16 w1 = (_Float16)r1;
                float r2 = (r1 - (float)w1) * 2048.0f;
                _Float16 w2 = (_Float16)r2;
                size_t o = ((size_t)blk * 64 + tid) * 4 + j;
                wp0[o] = w0; wp1[o] = w1; wp2[o] = w2;
            }
        }
    } else {
        wtail[tid] = wp[tid * F_ + 256];   // f = 256 column, f32 (no scaling)
    }
}

// Fused beamform(f32,LDS) + 3-term-split f16 MFMA GEMM + relu+log + BN sums.
// 512 threads = 8 waves; wave = beam b. Block = (n, 16-t tile).
// LDS 65.5 KB -> 2 blocks/CU; launch_bounds(512,2) -> VGPR cap 128, no spill.
__global__ __launch_bounds__(512, 2) void k_fused(
    const float* __restrict__ xr, const float* __restrict__ xi,
    const float* __restrict__ wr, const float* __restrict__ wi,
    const _Float16* __restrict__ wp0, const _Float16* __restrict__ wp1,
    const _Float16* __restrict__ wp2, const float* __restrict__ wtail,
    float* __restrict__ out, double* __restrict__ partials) {

    const int tid = threadIdx.x;
    const int bid = blockIdx.x;
    const int tt = bid % NT_;
    const int n  = bid / NT_;
    const int t0 = tt * TT_;

    __shared__ __attribute__((aligned(16))) float magS[2][TT_][MSTR];  // 33.8 KB
    __shared__ __attribute__((aligned(16))) _Float16 wfS[2][3][2560];  // 30 KB
    __shared__ float wtS[80];
    __shared__ float magT[TT_][B_];

    const int lane = tid & 63;
    const int wv   = tid >> 6;                // wave id == beam b

    const int sfr = tid >> 4;                 // staging f-row 0..31
    const int t_s = tid & 15;                 // staging t 0..15
    const int tg  = t0 + t_s;
    const bool tld = (tg < T_);

    f32x4 accM[5], acc1[5], acc2[5];
#pragma unroll
    for (int kt = 0; kt < 5; ++kt) {
        accM[kt] = (f32x4)0.0f;
        acc1[kt] = (f32x4)0.0f;
        acc2[kt] = (f32x4)0.0f;
    }

    const float* xrn = xr + (size_t)n * C_ * F_ * T_;
    const float* xin = xi + (size_t)n * C_ * F_ * T_;

    if (tid < 80) wtS[tid] = wtail[tid];

    // -------- prefetch x for chunk 0 (f = sfr) --------
    float pxr[C_], pxi[C_];
    if (tld) {
#pragma unroll
        for (int c = 0; c < C_; ++c) {
            pxr[c] = xrn[((size_t)c * F_ + sfr) * T_ + tg];
            pxi[c] = xin[((size_t)c * F_ + sfr) * T_ + tg];
        }
    }

    for (int ch = 0; ch < 8; ++ch) {
        const int f0 = ch * 32;
        const int f  = f0 + sfr;
        const int pb = ch & 1;

        // ---- stage w fragments: 3 terms x 2560 halves = 960 x 16B ----
#pragma unroll
        for (int r = 0; r < 2; ++r) {
            int idx = tid + r * 512;
            if (idx < 960) {
                int term = idx / 320;
                int u = idx - term * 320;
                const _Float16* src =
                    (term == 0 ? wp0 : (term == 1 ? wp1 : wp2)) + ch * 2560 + u * 8;
                *(half8*)&wfS[pb][term][u * 8] = *(const half8*)src;
            }
        }

        // ---- beamform mag (f32) into magS[pb]: 8 b at (f, tg) ----
        {
            float m[B_];
            if (tld) {
                const float* wrp = wr + (size_t)f * B_ * C_;
                const float* wip = wi + (size_t)f * B_ * C_;
#pragma unroll
                for (int b = 0; b < B_; ++b) {
                    float4 wrv = *(const float4*)(wrp + b * C_);
                    float4 wiv = *(const float4*)(wip + b * C_);
                    float br  = pxr[0] * wrv.x + pxr[1] * wrv.y + pxr[2] * wrv.z + pxr[3] * wrv.w
                              - pxi[0] * wiv.x - pxi[1] * wiv.y - pxi[2] * wiv.z - pxi[3] * wiv.w;
                    float bi2 = pxi[0] * wrv.x + pxi[1] * wrv.y + pxi[2] * wrv.z + pxi[3] * wrv.w
                              + pxr[0] * wiv.x + pxr[1] * wiv.y + pxr[2] * wiv.z + pxr[3] * wiv.w;
                    m[b] = sqrtf(br * br + bi2 * bi2 + 1e-5f);
                }
            } else {
#pragma unroll
                for (int b = 0; b < B_; ++b) m[b] = 0.f;
            }
            *(float4*)&magS[pb][t_s][sfr * 8] = make_float4(m[0], m[1], m[2], m[3]);
            *(float4*)&magS[pb][t_s][sfr * 8 + 4] = make_float4(m[4], m[5], m[6], m[7]);
        }

        // ---- prefetch x for ch+1 ----
        if (ch < 7 && tld) {
            const int f2 = f0 + 32 + sfr;
#pragma unroll
            for (int c = 0; c < C_; ++c) {
                pxr[c] = xrn[((size_t)c * F_ + f2) * T_ + tg];
                pxi[c] = xin[((size_t)c * F_ + f2) * T_ + tg];
            }
        }

        __syncthreads();

        // ---- MFMA GEMM (16x16x16f16, documented layout): 2 k-subtiles ----
        {
            const int tA = lane & 15;
            const int g  = lane >> 4;
#pragma unroll
            for (int ks = 0; ks < 2; ++ks) {
                half4 a0, a1, a2;
#pragma unroll
                for (int j = 0; j < 4; ++j) {
                    float v = magS[pb][tA][(ks * 16 + 4 * g + j) * 8 + wv];
                    _Float16 h0 = (_Float16)v;
                    float r1 = (v - (float)h0) * 2048.0f;
                    _Float16 h1 = (_Float16)r1;
                    float r2 = (r1 - (float)h1) * 2048.0f;
                    a0[j] = h0; a1[j] = h1; a2[j] = (_Float16)r2;
                }
#pragma unroll
                for (int kt = 0; kt < 5; ++kt) {
                    int fi = ((kt * 2 + ks) * 64 + lane) * 4;
                    half4 b0 = *(const half4*)&wfS[pb][0][fi];
                    half4 b1 = *(const half4*)&wfS[pb][1][fi];
                    half4 b2 = *(const half4*)&wfS[pb][2][fi];
                    accM[kt] = __builtin_amdgcn_mfma_f32_16x16x16f16(a0, b0, accM[kt], 0, 0, 0);
                    acc1[kt] = __builtin_amdgcn_mfma_f32_16x16x16f16(a0, b1, acc1[kt], 0, 0, 0);
                    acc1[kt] = __builtin_amdgcn_mfma_f32_16x16x16f16(a1, b0, acc1[kt], 0, 0, 0);
                    acc2[kt] = __builtin_amdgcn_mfma_f32_16x16x16f16(a0, b2, acc2[kt], 0, 0, 0);
                    acc2[kt] = __builtin_amdgcn_mfma_f32_16x16x16f16(a1, b1, acc2[kt], 0, 0, 0);
                    acc2[kt] = __builtin_amdgcn_mfma_f32_16x16x16f16(a2, b0, acc2[kt], 0, 0, 0);
                }
            }
        }
    }

    // ---- tail f = 256: f32 mag into magT ----
    if (tid < 128) {
        int trow = tid >> 3;
        int b = tid & 7;
        int t = t0 + trow;
        float v = 0.f;
        if (t < T_) {
            const float* wrp = wr + (size_t)(256 * B_ + b) * C_;
            const float* wip = wi + (size_t)(256 * B_ + b) * C_;
            float br = 0.f, bi2 = 0.f;
#pragma unroll
            for (int c = 0; c < C_; ++c) {
                float xrv = xrn[((size_t)c * F_ + 256) * T_ + t];
                float xiv = xin[((size_t)c * F_ + 256) * T_ + t];
                br  += xrv * wrp[c] - xiv * wip[c];
                bi2 += xiv * wrp[c] + xrv * wip[c];
            }
            v = sqrtf(br * br + bi2 * bi2 + 1e-5f);
        }
        magT[trow][b] = v;
    }
    __syncthreads();

    // ---- epilogue: combine 3-term accs (unscale) + tail, relu+log, BN ----
    const int col = lane & 15;
    const int g   = lane >> 4;
    float s1 = 0.f, s2 = 0.f;
#pragma unroll
    for (int kt = 0; kt < 5; ++kt) {
        f32x4 r = (accM[kt] + 4.8828125e-4f * acc1[kt]
                   + 2.384185791015625e-7f * acc2[kt]) * WUNSCALE;
#pragma unroll
        for (int reg = 0; reg < 4; ++reg) {
            int trow = 4 * g + reg;
            int t = t0 + trow;
            float sum = r[reg] + magT[trow][wv] * wtS[kt * 16 + col];
            if (t < T_) {
                float v = fmaxf(sum, 0.0f);
                v = __logf(v + 1e-5f);
                out[((size_t)n * T_ + t) * BK_ + wv * K_ + kt * 16 + col] = v;
                s1 += v;
                s2 += v * v;
            }
        }
    }
    double d1 = (double)s1, d2 = (double)s2;
#pragma unroll
    for (int off = 32; off; off >>= 1) {
        d1 += __shfl_xor(d1, off);
        d2 += __shfl_xor(d2, off);
    }
    if (lane == 0) {
        partials[(size_t)bid * 16 + wv] = d1;
        partials[(size_t)bid * 16 + 8 + wv] = d2;
    }
}

// ---------------- reduce partials -> per-channel scale/shift ----------------
__global__ __launch_bounds__(256) void k_bnstats(
    const double* __restrict__ partials,
    const float* __restrict__ gamma, const float* __restrict__ beta,
    float* __restrict__ ss) {
    const int b = threadIdx.x >> 5;
    const int i = threadIdx.x & 31;
    double s1 = 0.0, s2 = 0.0;
    for (int j = i; j < NBLK; j += 32) {
        s1 += partials[(size_t)j * 16 + b];
        s2 += partials[(size_t)j * 16 + 8 + b];
    }
#pragma unroll
    for (int off = 16; off; off >>= 1) {
        s1 += __shfl_down(s1, off);
        s2 += __shfl_down(s2, off);
    }
    if (i == 0) {
        const double cnt = (double)N_ * T_ * K_;
        double mean = s1 / cnt;
        double var = s2 / cnt - mean * mean;
        float scale = gamma[b] * (float)(1.0 / sqrt(var + 1e-5));
        float shift = beta[b] - (float)mean * scale;
        ss[b] = scale;
        ss[B_ + b] = shift;
    }
}

// ---------------- apply BN in place over d_out ----------------
__global__ __launch_bounds__(256) void k_bnapply(float* __restrict__ out,
                                                 const float* __restrict__ ss) {
    size_t i4 = (size_t)blockIdx.x * 256 + threadIdx.x;
    int k4 = (int)(i4 % (BK_ / 4));
    int b = k4 / (K_ / 4);
    float scale = ss[b], shift = ss[B_ + b];
    float4* p = (float4*)out + i4;
    float4 v = *p;
    v.x = v.x * scale + shift;
    v.y = v.y * scale + shift;
    v.z = v.z * scale + shift;
    v.w = v.w * scale + shift;
    *p = v;
}

extern "C" void kernel_launch(void* const* d_in, const int* in_sizes, int n_in,
                              void* d_out, int out_size, void* d_ws, size_t ws_size,
                              hipStream_t stream) {
    const float* xr = (const float*)d_in[0];
    const float* xi = (const float*)d_in[1];
    const float* wr = (const float*)d_in[2];
    const float* wi = (const float*)d_in[3];
    const float* w_proj = (const float*)d_in[4];
    const float* gamma = (const float*)d_in[5];
    const float* beta = (const float*)d_in[6];
    float* out = (float*)d_out;

    _Float16* wp0 = (_Float16*)((char*)d_ws + WP0_OFF);
    _Float16* wp1 = (_Float16*)((char*)d_ws + WP1_OFF);
    _Float16* wp2 = (_Float16*)((char*)d_ws + WP2_OFF);
    float* wtail = (float*)((char*)d_ws + WTAIL_OFF);
    double* partials = (double*)((char*)d_ws + PART_OFF);
    float* ss = (float*)((char*)d_ws + SS_OFF);

    k_wt<<<81, 80, 0, stream>>>(w_proj, wp0, wp1, wp2, wtail);
    k_fused<<<NBLK, 512, 0, stream>>>(xr, xi, wr, wi, wp0, wp1, wp2, wtail, out, partials);
    k_bnstats<<<1, 256, 0, stream>>>(partials, gamma, beta, ss);
    k_bnapply<<<10000, 256, 0, stream>>>(out, ss);
}